// Round 1
// baseline (540.056 us; speedup 1.0000x reference)
//
#include <hip/hip_runtime.h>
#include <hip/hip_bf16.h>
#include <stdint.h>

typedef unsigned short u16;
typedef short s16x8 __attribute__((ext_vector_type(8)));
typedef u16 u16x8 __attribute__((ext_vector_type(8)));
typedef float f32x4 __attribute__((ext_vector_type(4)));

__device__ __forceinline__ u16 f2bf(float f) {
  union { float f; uint32_t u; } c; c.f = f;
  uint32_t u = c.u;
  u = u + 0x7fffu + ((u >> 16) & 1u);   // round-to-nearest-even
  return (u16)(u >> 16);
}
__device__ __forceinline__ float bf2f(u16 b) {
  union { uint32_t u; float f; } c; c.u = ((uint32_t)b) << 16;
  return c.f;
}

// async global->LDS, 16B per lane. LDS dest must be wave-uniform base + lane*16.
__device__ __forceinline__ void gld_lds16(const u16* g, u16* l) {
  __builtin_amdgcn_global_load_lds(
      (const __attribute__((address_space(1))) uint32_t*)g,
      (__attribute__((address_space(3))) uint32_t*)l,
      16, 0, 0);
}

// ---------------------------------------------------------------------------
// fp32 -> bf16 convert, 8 elems/thread
// ---------------------------------------------------------------------------
__global__ __launch_bounds__(256) void cvt_f32_to_bf16(
    const float* __restrict__ in, u16* __restrict__ out, long n8) {
  long i = (long)blockIdx.x * blockDim.x + threadIdx.x;
  if (i >= n8) return;
  const float4 a = ((const float4*)in)[i * 2];
  const float4 b = ((const float4*)in)[i * 2 + 1];
  u16x8 r;
  r[0] = f2bf(a.x); r[1] = f2bf(a.y); r[2] = f2bf(a.z); r[3] = f2bf(a.w);
  r[4] = f2bf(b.x); r[5] = f2bf(b.y); r[6] = f2bf(b.z); r[7] = f2bf(b.w);
  *(u16x8*)&out[i * 8] = r;
}

// ---------------------------------------------------------------------------
// bf16 tiled transpose: in [z][R][C] -> out [z][C][R], 64x64 tiles
// ---------------------------------------------------------------------------
__global__ __launch_bounds__(256) void transpose64(
    const u16* __restrict__ in, u16* __restrict__ out, int R, int C) {
  __shared__ u16 t[64][66];
  const long ib = (long)blockIdx.z * (long)R * C;
  const int r0 = blockIdx.x * 64, c0 = blockIdx.y * 64;
  const int tid = threadIdx.x;
#pragma unroll
  for (int i = 0; i < 2; ++i) {
    const int ch = i * 256 + tid;         // 0..511
    const int r = ch >> 3, cc = ch & 7;
    const s16x8 v = *(const s16x8*)&in[ib + (long)(r0 + r) * C + c0 + cc * 8];
#pragma unroll
    for (int j = 0; j < 8; ++j) t[r][cc * 8 + j] = (u16)v[j];
  }
  __syncthreads();
#pragma unroll
  for (int i = 0; i < 2; ++i) {
    const int ch = i * 256 + tid;
    const int c = ch >> 3, rr = ch & 7;
    u16x8 r8;
#pragma unroll
    for (int j = 0; j < 8; ++j) r8[j] = t[rr * 8 + j][c];
    *(u16x8*)&out[ib + (long)(c0 + c) * R + r0 + rr * 8] = r8;
  }
}

// ---------------------------------------------------------------------------
// row softmax over 2048 cols, bf16 in/out (in place), fp32 math
// ---------------------------------------------------------------------------
__global__ __launch_bounds__(256) void softmax_rows(u16* __restrict__ S) {
  const long base = (long)blockIdx.x * 2048;
  const int tid = threadIdx.x;
  const int lane = tid & 63, wave = tid >> 6;
  u16x8 raw = *(const u16x8*)&S[base + tid * 8];
  float v[8];
#pragma unroll
  for (int j = 0; j < 8; ++j) v[j] = bf2f(raw[j]);
  float m = v[0];
#pragma unroll
  for (int j = 1; j < 8; ++j) m = fmaxf(m, v[j]);
#pragma unroll
  for (int off = 32; off >= 1; off >>= 1) m = fmaxf(m, __shfl_xor(m, off));
  __shared__ float red[8];
  if (lane == 0) red[wave] = m;
  __syncthreads();
  m = fmaxf(fmaxf(red[0], red[1]), fmaxf(red[2], red[3]));
  float s = 0.f;
#pragma unroll
  for (int j = 0; j < 8; ++j) { v[j] = __expf(v[j] - m); s += v[j]; }
#pragma unroll
  for (int off = 32; off >= 1; off >>= 1) s += __shfl_xor(s, off);
  if (lane == 0) red[4 + wave] = s;
  __syncthreads();
  s = (red[4] + red[5]) + (red[6] + red[7]);
  const float inv = 1.f / s;
#pragma unroll
  for (int j = 0; j < 8; ++j) raw[j] = f2bf(v[j] * inv);
  *(u16x8*)&S[base + tid * 8] = raw;
}

// ---------------------------------------------------------------------------
// gemm_bt: C[b][m][n] = sum_k A[b][m][k] * B[b][n][k]  (both row-major [rows][K])
// 128x128 tile, BK=64, 256 threads = 4 waves (2x2), 16x16x32 bf16 MFMA.
// Epilogue: *scale, +bias[n], mask==0 -> -1e30, store bf16 or fp32.
// Requires M%128==0, N%128==0, K%64==0 (true for all shapes here).
// ---------------------------------------------------------------------------
template<bool HAS_BIAS, bool HAS_MASK, bool OUT_F32>
__global__ __launch_bounds__(256) void gemm_bt_k(
    const u16* __restrict__ A, const u16* __restrict__ B,
    const float* __restrict__ bias, const int* __restrict__ mask,
    void* __restrict__ Cv, int M, int N, int K,
    long sA, long sB, long sC, long sMask, float scale) {
  constexpr int BK = 64;
  __shared__ __align__(16) u16 As[128 * BK];
  __shared__ __align__(16) u16 Bs[128 * BK];
  const int b = blockIdx.z;
  const u16* Ab = A + (long)b * sA;
  const u16* Bb = B + (long)b * sB;
  const int tid = threadIdx.x;
  const int lane = tid & 63;
  const int wave = tid >> 6;
  const int wm = wave >> 1, wn = wave & 1;       // 2x2 waves, 64x64 each
  const int bm = blockIdx.x * 128, bn = blockIdx.y * 128;

  f32x4 acc[4][4] = {};

  const int ktn = K / BK;
  for (int kt = 0; kt < ktn; ++kt) {
    const int k0 = kt * BK;
    // stage A tile: 128x64 bf16 = 1024 16B-chunks, 4 per thread
#pragma unroll
    for (int i = 0; i < 4; ++i) {
      const int c = i * 256 + tid;
      gld_lds16(Ab + (long)(bm + (c >> 3)) * K + k0 + (c & 7) * 8, &As[c * 8]);
    }
#pragma unroll
    for (int i = 0; i < 4; ++i) {
      const int c = i * 256 + tid;
      gld_lds16(Bb + (long)(bn + (c >> 3)) * K + k0 + (c & 7) * 8, &Bs[c * 8]);
    }
    asm volatile("s_waitcnt vmcnt(0)" ::: "memory");
    __syncthreads();
#pragma unroll
    for (int ks = 0; ks < 2; ++ks) {
      const int kb = ks * 32 + (lane >> 4) * 8;   // k-base for this lane group
      s16x8 af[4], bfr[4];
#pragma unroll
      for (int mi = 0; mi < 4; ++mi)
        af[mi] = *(const s16x8*)&As[(wm * 64 + mi * 16 + (lane & 15)) * BK + kb];
#pragma unroll
      for (int ni = 0; ni < 4; ++ni)
        bfr[ni] = *(const s16x8*)&Bs[(wn * 64 + ni * 16 + (lane & 15)) * BK + kb];
#pragma unroll
      for (int mi = 0; mi < 4; ++mi)
#pragma unroll
        for (int ni = 0; ni < 4; ++ni)
          acc[mi][ni] = __builtin_amdgcn_mfma_f32_16x16x32_bf16(
              af[mi], bfr[ni], acc[mi][ni], 0, 0, 0);
    }
    __syncthreads();
  }

  // epilogue: C/D layout col = lane&15, row = (lane>>4)*4 + j  [m89-verified]
  const long cb = (long)b * sC;
#pragma unroll
  for (int mi = 0; mi < 4; ++mi) {
#pragma unroll
    for (int ni = 0; ni < 4; ++ni) {
      const int row0 = bm + wm * 64 + mi * 16 + ((lane >> 4) * 4);
      const int col = bn + wn * 64 + ni * 16 + (lane & 15);
      const float bv = HAS_BIAS ? bias[col] : 0.f;
#pragma unroll
      for (int j = 0; j < 4; ++j) {
        const int row = row0 + j;
        float x = acc[mi][ni][j] * scale + bv;
        if (HAS_MASK) {
          if (mask[(long)b * sMask + (long)row * N + col] == 0) x = -1e30f;
        }
        if (OUT_F32)
          ((float*)Cv)[cb + (long)row * N + col] = x;
        else
          ((u16*)Cv)[cb + (long)row * N + col] = f2bf(x);
      }
    }
  }
}

// ---------------------------------------------------------------------------
extern "C" void kernel_launch(void* const* d_in, const int* in_sizes, int n_in,
                              void* d_out, int out_size, void* d_ws, size_t ws_size,
                              hipStream_t stream) {
  const float* query = (const float*)d_in[0];   // [8,2048,1024]
  const float* kv    = (const float*)d_in[1];   // [8,2048,1024]
  const int*   mask  = (const int*)d_in[2];     // [8,2048,2048]
  const float* Wq = (const float*)d_in[3];
  const float* bq = (const float*)d_in[4];
  const float* Wk = (const float*)d_in[5];
  const float* bk = (const float*)d_in[6];
  const float* Wv = (const float*)d_in[7];
  const float* bv = (const float*)d_in[8];
  const float* Wo = (const float*)d_in[9];
  const float* bo = (const float*)d_in[10];
  float* out = (float*)d_out;

  char* ws = (char*)d_ws;
  const size_t MB = (size_t)1 << 20;
  // workspace layout (232 MB total, with region reuse):
  u16* qbf  = (u16*)(ws + 0);          // 32MB query bf16; later reused as O
  u16* kvbf = (u16*)(ws + 32 * MB);    // 32MB kv bf16;   later reused as Vt
  u16* wq   = (u16*)(ws + 64 * MB);    // 2MB each
  u16* wk   = (u16*)(ws + 66 * MB);
  u16* wv   = (u16*)(ws + 68 * MB);
  u16* wo   = (u16*)(ws + 70 * MB);
  u16* Q    = (u16*)(ws + 72 * MB);    // 32MB
  u16* Kb   = (u16*)(ws + 104 * MB);   // 32MB
  u16* V    = (u16*)(ws + 136 * MB);   // 32MB
  u16* S    = (u16*)(ws + 168 * MB);   // 64MB  [8][2048][2048] bf16
  u16* Vt   = kvbf;                    // [8][1024][2048] bf16
  u16* O    = qbf;                     // [8][2048][1024] bf16

  const long sQK = (long)2048 * 1024;   // per-batch Q/K/V/O stride
  const long sS  = (long)2048 * 2048;   // per-batch S stride

  // 1) converts
  cvt_f32_to_bf16<<<8192, 256, 0, stream>>>(query, qbf, 2097152);
  cvt_f32_to_bf16<<<8192, 256, 0, stream>>>(kv, kvbf, 2097152);
  cvt_f32_to_bf16<<<512, 256, 0, stream>>>(Wq, wq, 131072);
  cvt_f32_to_bf16<<<512, 256, 0, stream>>>(Wk, wk, 131072);
  cvt_f32_to_bf16<<<512, 256, 0, stream>>>(Wv, wv, 131072);
  cvt_f32_to_bf16<<<512, 256, 0, stream>>>(Wo, wo, 131072);

  // 2) projections: X @ W^T + b   (M=16384, N=1024, K=1024)
  gemm_bt_k<true, false, false><<<dim3(128, 8, 1), 256, 0, stream>>>(
      qbf, wq, bq, nullptr, Q, 16384, 1024, 1024, 0, 0, 0, 0, 1.f);
  gemm_bt_k<true, false, false><<<dim3(128, 8, 1), 256, 0, stream>>>(
      kvbf, wk, bk, nullptr, Kb, 16384, 1024, 1024, 0, 0, 0, 0, 1.f);
  gemm_bt_k<true, false, false><<<dim3(128, 8, 1), 256, 0, stream>>>(
      kvbf, wv, bv, nullptr, V, 16384, 1024, 1024, 0, 0, 0, 0, 1.f);

  // 3) V -> Vt  ([2048][1024] -> [1024][2048] per batch)
  transpose64<<<dim3(32, 16, 8), 256, 0, stream>>>(V, Vt, 2048, 1024);

  // 4) S = (Q K^T) * 1/32, masked    (per batch 2048x2048, K=1024)
  gemm_bt_k<false, true, false><<<dim3(16, 16, 8), 256, 0, stream>>>(
      Q, Kb, nullptr, mask, S, 2048, 2048, 1024, sQK, sQK, sS, sS, 0.03125f);

  // 5) row softmax (in place on S)
  softmax_rows<<<16384, 256, 0, stream>>>(S);

  // 6) O = P @ V     (A=S [2048][2048], Bt=Vt [1024 rows][2048 k])
  gemm_bt_k<false, false, false><<<dim3(16, 8, 8), 256, 0, stream>>>(
      S, Vt, nullptr, nullptr, O, 2048, 1024, 2048, sS, sQK, sQK, 0, 1.f);

  // 7) out = O @ Wo^T + bo   (fp32 output)
  gemm_bt_k<true, false, true><<<dim3(128, 8, 1), 256, 0, stream>>>(
      O, wo, bo, nullptr, out, 16384, 1024, 1024, 0, 0, 0, 0, 1.f);
}

// Round 3
// 427.435 us; speedup vs baseline: 1.2635x; 1.2635x over previous
//
#include <hip/hip_runtime.h>
#include <hip/hip_bf16.h>
#include <stdint.h>

typedef unsigned short u16;
typedef short s16x8 __attribute__((ext_vector_type(8)));
typedef u16 u16x8 __attribute__((ext_vector_type(8)));
typedef float f32x4 __attribute__((ext_vector_type(4)));

__device__ __forceinline__ u16 f2bf(float f) {
  union { float f; uint32_t u; } c; c.f = f;
  uint32_t u = c.u;
  u = u + 0x7fffu + ((u >> 16) & 1u);   // round-to-nearest-even
  return (u16)(u >> 16);
}
__device__ __forceinline__ float bf2f(u16 b) {
  union { uint32_t u; float f; } c; c.u = ((uint32_t)b) << 16;
  return c.f;
}

// async global->LDS, 16B per lane. LDS dest must be wave-uniform base + lane*16.
__device__ __forceinline__ void gld_lds16(const u16* g, u16* l) {
  __builtin_amdgcn_global_load_lds(
      (const __attribute__((address_space(1))) uint32_t*)g,
      (__attribute__((address_space(3))) uint32_t*)l,
      16, 0, 0);
}

// ---------------------------------------------------------------------------
// fp32 -> bf16 convert, 8 elems/thread
// ---------------------------------------------------------------------------
__global__ __launch_bounds__(256) void cvt_f32_to_bf16(
    const float* __restrict__ in, u16* __restrict__ out, long n8) {
  long i = (long)blockIdx.x * blockDim.x + threadIdx.x;
  if (i >= n8) return;
  const float4 a = ((const float4*)in)[i * 2];
  const float4 b = ((const float4*)in)[i * 2 + 1];
  u16x8 r;
  r[0] = f2bf(a.x); r[1] = f2bf(a.y); r[2] = f2bf(a.z); r[3] = f2bf(a.w);
  r[4] = f2bf(b.x); r[5] = f2bf(b.y); r[6] = f2bf(b.z); r[7] = f2bf(b.w);
  *(u16x8*)&out[i * 8] = r;
}

// ---------------------------------------------------------------------------
// bf16 tiled transpose: in [z][R][C] -> out [z][C][R], 64x64 tiles
// ---------------------------------------------------------------------------
__global__ __launch_bounds__(256) void transpose64(
    const u16* __restrict__ in, u16* __restrict__ out, int R, int C) {
  __shared__ u16 t[64][66];
  const long ib = (long)blockIdx.z * (long)R * C;
  const int r0 = blockIdx.x * 64, c0 = blockIdx.y * 64;
  const int tid = threadIdx.x;
#pragma unroll
  for (int i = 0; i < 2; ++i) {
    const int ch = i * 256 + tid;
    const int r = ch >> 3, cc = ch & 7;
    const s16x8 v = *(const s16x8*)&in[ib + (long)(r0 + r) * C + c0 + cc * 8];
#pragma unroll
    for (int j = 0; j < 8; ++j) t[r][cc * 8 + j] = (u16)v[j];
  }
  __syncthreads();
#pragma unroll
  for (int i = 0; i < 2; ++i) {
    const int ch = i * 256 + tid;
    const int c = ch >> 3, rr = ch & 7;
    u16x8 r8;
#pragma unroll
    for (int j = 0; j < 8; ++j) r8[j] = t[rr * 8 + j][c];
    *(u16x8*)&out[ib + (long)(c0 + c) * R + r0 + rr * 8] = r8;
  }
}

// ---------------------------------------------------------------------------
// masked row softmax over 2048 cols, bf16 in/out (in place), fp32 math.
// mask row (int32, 0 => -inf) applied here, vectorized int4 loads.
// ---------------------------------------------------------------------------
__global__ __launch_bounds__(256) void softmax_mask_rows(
    u16* __restrict__ S, const int* __restrict__ mask) {
  const long base = (long)blockIdx.x * 2048;
  const int tid = threadIdx.x;
  const int lane = tid & 63, wave = tid >> 6;
  u16x8 raw = *(const u16x8*)&S[base + tid * 8];
  const int4 m0 = ((const int4*)(mask + base))[tid * 2];
  const int4 m1 = ((const int4*)(mask + base))[tid * 2 + 1];
  float v[8];
  v[0] = m0.x ? bf2f(raw[0]) : -1e30f;
  v[1] = m0.y ? bf2f(raw[1]) : -1e30f;
  v[2] = m0.z ? bf2f(raw[2]) : -1e30f;
  v[3] = m0.w ? bf2f(raw[3]) : -1e30f;
  v[4] = m1.x ? bf2f(raw[4]) : -1e30f;
  v[5] = m1.y ? bf2f(raw[5]) : -1e30f;
  v[6] = m1.z ? bf2f(raw[6]) : -1e30f;
  v[7] = m1.w ? bf2f(raw[7]) : -1e30f;
  float m = v[0];
#pragma unroll
  for (int j = 1; j < 8; ++j) m = fmaxf(m, v[j]);
#pragma unroll
  for (int off = 32; off >= 1; off >>= 1) m = fmaxf(m, __shfl_xor(m, off));
  __shared__ float red[8];
  if (lane == 0) red[wave] = m;
  __syncthreads();
  m = fmaxf(fmaxf(red[0], red[1]), fmaxf(red[2], red[3]));
  float s = 0.f;
#pragma unroll
  for (int j = 0; j < 8; ++j) { v[j] = __expf(v[j] - m); s += v[j]; }
#pragma unroll
  for (int off = 32; off >= 1; off >>= 1) s += __shfl_xor(s, off);
  if (lane == 0) red[4 + wave] = s;
  __syncthreads();
  s = (red[4] + red[5]) + (red[6] + red[7]);
  const float inv = 1.f / s;
#pragma unroll
  for (int j = 0; j < 8; ++j) raw[j] = f2bf(v[j] * inv);
  *(u16x8*)&S[base + tid * 8] = raw;
}

// ---------------------------------------------------------------------------
// 256x256x64 8-phase GEMM (bt): C[b][m][n] = sum_k A[b][m][k]*B[b][n][k].
// 512 thr = 8 waves (2M x 4N), per-wave 128x64 out, acc[8][4] f32x4.
// LDS 128 KiB: 2 dbuf x (A[256][64] + B[256][64]) bf16, T2 chunk-XOR swizzle
// (linear gld_lds dest + pre-swizzled global source + XOR on ds_read).
// 4 phases/K-tile (one output quadrant each: 12 ds_read_b128 + 1 quarter-tile
// stage + barrier + 16 MFMA + barrier); counted vmcnt(4) once per tile.
// Stage schedule (quarter-tiles, region-hazard-free by induction:
// at each end-of-tile vmcnt(4) exactly Ae(t+2),Be(t+2) remain in flight):
//   ph1: A_late(t+1)->nxt    ph2: B_late(t+1)->nxt
//   ph3: A_early(t+2)->cur   ph4: B_early(t+2)->cur, then vmcnt(4); barrier
// A_early = rows {0-63,128-191} (read only in QM=0 phases 1-2);
// B_early = rows {0-31,64-95,128-159,192-223} (read only in QN=0 phases 1,3).
// ---------------------------------------------------------------------------
__device__ __forceinline__ s16x8 ldsfrag(const u16* p, int r, int c8) {
  return *(const s16x8*)&p[r * 64 + ((c8 ^ (r & 7)) << 3)];
}

template<int MAT, int LATE>
__device__ __forceinline__ void stage_chunk(const u16* __restrict__ gb, int row0,
                                            int K, int k0, u16* lbuf, int tid) {
#pragma unroll
  for (int i = 0; i < 2; ++i) {
    const int f = i * 512 + tid;
    const int rl = f >> 3, s = f & 7;
    int r;
    if (MAT == 0) r = (rl & 63) + ((rl >> 6) << 7) + (LATE ? 64 : 0);
    else          r = (rl & 31) + ((rl >> 5) << 6) + (LATE ? 32 : 0);
    const int gc = (s ^ (r & 7)) << 3;      // pre-swizzled global col chunk
    gld_lds16(gb + (long)(row0 + r) * K + k0 + gc, lbuf + r * 64 + s * 8);
  }
}

#define GFENCE asm volatile("" ::: "memory")

template<int QM, int QN, typename FS, typename FB>
__device__ __forceinline__ void phase_fn(
    const u16* lA, const u16* lB, f32x4 (&acc)[8][4],
    int wm, int wn, int lr, int lk, FS&& stage, FB&& boundary) {
  s16x8 af[4][2], bg[2][2];
#pragma unroll
  for (int mi = 0; mi < 4; ++mi)
#pragma unroll
    for (int ks = 0; ks < 2; ++ks)
      af[mi][ks] = ldsfrag(lA, wm * 128 + QM * 64 + mi * 16 + lr, ks * 4 + lk);
#pragma unroll
  for (int ni = 0; ni < 2; ++ni)
#pragma unroll
    for (int ks = 0; ks < 2; ++ks)
      bg[ni][ks] = ldsfrag(lB, wn * 64 + QN * 32 + ni * 16 + lr, ks * 4 + lk);
  stage();
  GFENCE; __builtin_amdgcn_s_barrier(); GFENCE;
  __builtin_amdgcn_s_setprio(1);
#pragma unroll
  for (int mi = 0; mi < 4; ++mi)
#pragma unroll
    for (int ni = 0; ni < 2; ++ni) {
      acc[QM * 4 + mi][QN * 2 + ni] = __builtin_amdgcn_mfma_f32_16x16x32_bf16(
          af[mi][0], bg[ni][0], acc[QM * 4 + mi][QN * 2 + ni], 0, 0, 0);
      acc[QM * 4 + mi][QN * 2 + ni] = __builtin_amdgcn_mfma_f32_16x16x32_bf16(
          af[mi][1], bg[ni][1], acc[QM * 4 + mi][QN * 2 + ni], 0, 0, 0);
    }
  __builtin_amdgcn_s_setprio(0);
  boundary();
  GFENCE; __builtin_amdgcn_s_barrier(); GFENCE;
}

template<bool HAS_BIAS, bool OUT_F32>
__global__ __launch_bounds__(512, 1) void gemm256(
    const u16* __restrict__ A, const u16* __restrict__ B,
    const float* __restrict__ bias, void* __restrict__ Cv,
    int M, int N, int K, long sA, long sB, long sC, float scale) {
  __shared__ __align__(16) u16 lds[2][2][256 * 64];
  const int b = blockIdx.z;
  const u16* Ab = A + (long)b * sA;
  const u16* Bb = B + (long)b * sB;
  const int tid = threadIdx.x;
  const int lane = tid & 63, wave = tid >> 6;
  const int wm = wave >> 2, wn = wave & 3;
  const int lr = lane & 15, lk = lane >> 4;
  const int bm = blockIdx.x * 256, bn = blockIdx.y * 256;
  const int NT = K >> 6;

  f32x4 acc[8][4] = {};

  // prologue: tile0 all 4 chunks -> buf0, tile1 early chunks -> buf1
  stage_chunk<0, 0>(Ab, bm, K, 0, lds[0][0], tid);
  stage_chunk<1, 0>(Bb, bn, K, 0, lds[0][1], tid);
  stage_chunk<0, 1>(Ab, bm, K, 0, lds[0][0], tid);
  stage_chunk<1, 1>(Bb, bn, K, 0, lds[0][1], tid);
  if (NT > 1) {
    stage_chunk<0, 0>(Ab, bm, K, 64, lds[1][0], tid);
    stage_chunk<1, 0>(Bb, bn, K, 64, lds[1][1], tid);
    asm volatile("s_waitcnt vmcnt(4)" ::: "memory");
  } else {
    asm volatile("s_waitcnt vmcnt(0)" ::: "memory");
  }
  __builtin_amdgcn_s_barrier();
  GFENCE;

  for (int t = 0; t < NT; ++t) {
    const int cur = t & 1, nxt = cur ^ 1;
    const int k1 = (t + 1) << 6, k2 = (t + 2) << 6;
    const u16* lA = lds[cur][0];
    const u16* lB = lds[cur][1];
    phase_fn<0, 0>(lA, lB, acc, wm, wn, lr, lk,
        [&]() { if (t + 1 < NT) stage_chunk<0, 1>(Ab, bm, K, k1, lds[nxt][0], tid); },
        [&]() {});
    phase_fn<0, 1>(lA, lB, acc, wm, wn, lr, lk,
        [&]() { if (t + 1 < NT) stage_chunk<1, 1>(Bb, bn, K, k1, lds[nxt][1], tid); },
        [&]() {});
    phase_fn<1, 0>(lA, lB, acc, wm, wn, lr, lk,
        [&]() { if (t + 2 < NT) stage_chunk<0, 0>(Ab, bm, K, k2, lds[cur][0], tid); },
        [&]() {});
    phase_fn<1, 1>(lA, lB, acc, wm, wn, lr, lk,
        [&]() { if (t + 2 < NT) stage_chunk<1, 0>(Bb, bn, K, k2, lds[cur][1], tid); },
        [&]() {
          if (t + 2 < NT)      { asm volatile("s_waitcnt vmcnt(4)" ::: "memory"); }
          else if (t + 1 < NT) { asm volatile("s_waitcnt vmcnt(0)" ::: "memory"); }
        });
  }

  // epilogue: C/D layout col = lane&15, row = (lane>>4)*4 + j
  const long cb = (long)b * sC;
#pragma unroll
  for (int mi = 0; mi < 8; ++mi) {
#pragma unroll
    for (int ni = 0; ni < 4; ++ni) {
      const int row0 = bm + wm * 128 + mi * 16 + (lk << 2);
      const int col = bn + wn * 64 + ni * 16 + lr;
      const float bv = HAS_BIAS ? bias[col] : 0.f;
#pragma unroll
      for (int j = 0; j < 4; ++j) {
        const float x = acc[mi][ni][j] * scale + bv;
        if (OUT_F32)
          ((float*)Cv)[cb + (long)(row0 + j) * N + col] = x;
        else
          ((u16*)Cv)[cb + (long)(row0 + j) * N + col] = f2bf(x);
      }
    }
  }
}

// ---------------------------------------------------------------------------
extern "C" void kernel_launch(void* const* d_in, const int* in_sizes, int n_in,
                              void* d_out, int out_size, void* d_ws, size_t ws_size,
                              hipStream_t stream) {
  const float* query = (const float*)d_in[0];   // [8,2048,1024]
  const float* kv    = (const float*)d_in[1];   // [8,2048,1024]
  const int*   mask  = (const int*)d_in[2];     // [8,2048,2048]
  const float* Wq = (const float*)d_in[3];
  const float* bq = (const float*)d_in[4];
  const float* Wk = (const float*)d_in[5];
  const float* bk = (const float*)d_in[6];
  const float* Wv = (const float*)d_in[7];
  const float* bv = (const float*)d_in[8];
  const float* Wo = (const float*)d_in[9];
  const float* bo = (const float*)d_in[10];
  float* out = (float*)d_out;

  char* ws = (char*)d_ws;
  const size_t MB = (size_t)1 << 20;
  u16* qbf  = (u16*)(ws + 0);          // 32MB query bf16; later reused as O
  u16* kvbf = (u16*)(ws + 32 * MB);    // 32MB kv bf16;   later reused as Vt
  u16* wq   = (u16*)(ws + 64 * MB);
  u16* wk   = (u16*)(ws + 66 * MB);
  u16* wv   = (u16*)(ws + 68 * MB);
  u16* wo   = (u16*)(ws + 70 * MB);
  u16* Q    = (u16*)(ws + 72 * MB);    // 32MB
  u16* Kb   = (u16*)(ws + 104 * MB);   // 32MB
  u16* V    = (u16*)(ws + 136 * MB);   // 32MB
  u16* S    = (u16*)(ws + 168 * MB);   // 64MB  [8][2048][2048] bf16
  u16* Vt   = kvbf;                    // [8][1024][2048] bf16
  u16* O    = qbf;                     // [8][2048][1024] bf16

  const long sQK = (long)2048 * 1024;
  const long sS  = (long)2048 * 2048;

  // 1) converts
  cvt_f32_to_bf16<<<8192, 256, 0, stream>>>(query, qbf, 2097152);
  cvt_f32_to_bf16<<<8192, 256, 0, stream>>>(kv, kvbf, 2097152);
  cvt_f32_to_bf16<<<512, 256, 0, stream>>>(Wq, wq, 131072);
  cvt_f32_to_bf16<<<512, 256, 0, stream>>>(Wk, wk, 131072);
  cvt_f32_to_bf16<<<512, 256, 0, stream>>>(Wv, wv, 131072);
  cvt_f32_to_bf16<<<512, 256, 0, stream>>>(Wo, wo, 131072);

  // 2) projections: X @ W^T + b   (M=16384, N=1024, K=1024)
  gemm256<true, false><<<dim3(64, 4, 1), 512, 0, stream>>>(
      qbf, wq, bq, Q, 16384, 1024, 1024, 0, 0, 0, 1.f);
  gemm256<true, false><<<dim3(64, 4, 1), 512, 0, stream>>>(
      kvbf, wk, bk, Kb, 16384, 1024, 1024, 0, 0, 0, 1.f);
  gemm256<true, false><<<dim3(64, 4, 1), 512, 0, stream>>>(
      kvbf, wv, bv, V, 16384, 1024, 1024, 0, 0, 0, 1.f);

  // 3) V -> Vt  ([2048][1024] -> [1024][2048] per batch)
  transpose64<<<dim3(32, 16, 8), 256, 0, stream>>>(V, Vt, 2048, 1024);

  // 4) S = (Q K^T) * 1/32 (unmasked; mask applied in softmax)
  gemm256<false, false><<<dim3(8, 8, 8), 512, 0, stream>>>(
      Q, Kb, nullptr, S, 2048, 2048, 1024, sQK, sQK, sS, 0.03125f);

  // 5) masked row softmax (in place on S)
  softmax_mask_rows<<<16384, 256, 0, stream>>>(S, mask);

  // 6) O = P @ V
  gemm256<false, false><<<dim3(8, 4, 8), 512, 0, stream>>>(
      S, Vt, nullptr, O, 2048, 1024, 2048, sS, sQK, sQK, 1.f);

  // 7) out = O @ Wo^T + bo   (fp32 output)
  gemm256<true, true><<<dim3(64, 4, 1), 512, 0, stream>>>(
      O, wo, bo, out, 16384, 1024, 1024, 0, 0, 0, 1.f);
}

// Round 4
// 408.769 us; speedup vs baseline: 1.3212x; 1.0457x over previous
//
#include <hip/hip_runtime.h>
#include <hip/hip_bf16.h>
#include <stdint.h>

typedef unsigned short u16;
typedef short s16x8 __attribute__((ext_vector_type(8)));
typedef u16 u16x8 __attribute__((ext_vector_type(8)));
typedef u16 u16x4 __attribute__((ext_vector_type(4)));
typedef float f32x4 __attribute__((ext_vector_type(4)));

__device__ __forceinline__ u16 f2bf(float f) {
  union { float f; uint32_t u; } c; c.f = f;
  uint32_t u = c.u;
  u = u + 0x7fffu + ((u >> 16) & 1u);   // round-to-nearest-even
  return (u16)(u >> 16);
}
__device__ __forceinline__ float bf2f(u16 b) {
  union { uint32_t u; float f; } c; c.u = ((uint32_t)b) << 16;
  return c.f;
}

// async global->LDS, 16B per lane. LDS dest must be wave-uniform base + lane*16.
__device__ __forceinline__ void gld_lds16(const u16* g, u16* l) {
  __builtin_amdgcn_global_load_lds(
      (const __attribute__((address_space(1))) uint32_t*)g,
      (__attribute__((address_space(3))) uint32_t*)l,
      16, 0, 0);
}

// ---------------------------------------------------------------------------
// fp32 -> bf16 convert, 8 elems/thread
// ---------------------------------------------------------------------------
__global__ __launch_bounds__(256) void cvt_f32_to_bf16(
    const float* __restrict__ in, u16* __restrict__ out, long n8) {
  long i = (long)blockIdx.x * blockDim.x + threadIdx.x;
  if (i >= n8) return;
  const float4 a = ((const float4*)in)[i * 2];
  const float4 b = ((const float4*)in)[i * 2 + 1];
  u16x8 r;
  r[0] = f2bf(a.x); r[1] = f2bf(a.y); r[2] = f2bf(a.z); r[3] = f2bf(a.w);
  r[4] = f2bf(b.x); r[5] = f2bf(b.y); r[6] = f2bf(b.z); r[7] = f2bf(b.w);
  *(u16x8*)&out[i * 8] = r;
}

// ---------------------------------------------------------------------------
// masked row softmax over 2048 cols, bf16 in/out (in place), fp32 math.
// ---------------------------------------------------------------------------
__global__ __launch_bounds__(256) void softmax_mask_rows(
    u16* __restrict__ S, const int* __restrict__ mask) {
  const long base = (long)blockIdx.x * 2048;
  const int tid = threadIdx.x;
  const int lane = tid & 63, wave = tid >> 6;
  u16x8 raw = *(const u16x8*)&S[base + tid * 8];
  const int4 m0 = ((const int4*)(mask + base))[tid * 2];
  const int4 m1 = ((const int4*)(mask + base))[tid * 2 + 1];
  float v[8];
  v[0] = m0.x ? bf2f(raw[0]) : -1e30f;
  v[1] = m0.y ? bf2f(raw[1]) : -1e30f;
  v[2] = m0.z ? bf2f(raw[2]) : -1e30f;
  v[3] = m0.w ? bf2f(raw[3]) : -1e30f;
  v[4] = m1.x ? bf2f(raw[4]) : -1e30f;
  v[5] = m1.y ? bf2f(raw[5]) : -1e30f;
  v[6] = m1.z ? bf2f(raw[6]) : -1e30f;
  v[7] = m1.w ? bf2f(raw[7]) : -1e30f;
  float m = v[0];
#pragma unroll
  for (int j = 1; j < 8; ++j) m = fmaxf(m, v[j]);
#pragma unroll
  for (int off = 32; off >= 1; off >>= 1) m = fmaxf(m, __shfl_xor(m, off));
  __shared__ float red[8];
  if (lane == 0) red[wave] = m;
  __syncthreads();
  m = fmaxf(fmaxf(red[0], red[1]), fmaxf(red[2], red[3]));
  float s = 0.f;
#pragma unroll
  for (int j = 0; j < 8; ++j) { v[j] = __expf(v[j] - m); s += v[j]; }
#pragma unroll
  for (int off = 32; off >= 1; off >>= 1) s += __shfl_xor(s, off);
  if (lane == 0) red[4 + wave] = s;
  __syncthreads();
  s = (red[4] + red[5]) + (red[6] + red[7]);
  const float inv = 1.f / s;
#pragma unroll
  for (int j = 0; j < 8; ++j) raw[j] = f2bf(v[j] * inv);
  *(u16x8*)&S[base + tid * 8] = raw;
}

// ---------------------------------------------------------------------------
// 256x256x64 8-phase GEMM (bt): C[b][m][n] = sum_k A[b][m][k]*B[b][n][k].
// 512 thr = 8 waves (2M x 4N); LDS 128 KiB 2x dbuf; T2 chunk-XOR swizzle;
// counted vmcnt(4) at tile boundary only (see round-2 schedule proof).
// T1: XCD-aware bijective remap of dispatch id -> (b, bm, bn): each XCD gets
// a contiguous chunk ordered z-major then x-major (one batch per XCD for the
// attention GEMMs; an 8-bm x all-bn panel for the projections).
// MODE: 0 = bf16 out; 1 = f32 out; 2 = split KV (cols<1024 -> Cv bf16
// ldC=1024; cols>=1024 -> Cv2 TRANSPOSED bf16 [batch][col][row], 2048
// rows/batch, u16x4 vector stores).
// ---------------------------------------------------------------------------
__device__ __forceinline__ s16x8 ldsfrag(const u16* p, int r, int c8) {
  return *(const s16x8*)&p[r * 64 + ((c8 ^ (r & 7)) << 3)];
}

template<int MAT, int LATE>
__device__ __forceinline__ void stage_chunk(const u16* __restrict__ gb, int row0,
                                            int K, int k0, u16* lbuf, int tid) {
#pragma unroll
  for (int i = 0; i < 2; ++i) {
    const int f = i * 512 + tid;
    const int rl = f >> 3, s = f & 7;
    int r;
    if (MAT == 0) r = (rl & 63) + ((rl >> 6) << 7) + (LATE ? 64 : 0);
    else          r = (rl & 31) + ((rl >> 5) << 6) + (LATE ? 32 : 0);
    const int gc = (s ^ (r & 7)) << 3;      // pre-swizzled global col chunk
    gld_lds16(gb + (long)(row0 + r) * K + k0 + gc, lbuf + r * 64 + s * 8);
  }
}

#define GFENCE asm volatile("" ::: "memory")

template<int QM, int QN, typename FS, typename FB>
__device__ __forceinline__ void phase_fn(
    const u16* lA, const u16* lB, f32x4 (&acc)[8][4],
    int wm, int wn, int lr, int lk, FS&& stage, FB&& boundary) {
  s16x8 af[4][2], bg[2][2];
#pragma unroll
  for (int mi = 0; mi < 4; ++mi)
#pragma unroll
    for (int ks = 0; ks < 2; ++ks)
      af[mi][ks] = ldsfrag(lA, wm * 128 + QM * 64 + mi * 16 + lr, ks * 4 + lk);
#pragma unroll
  for (int ni = 0; ni < 2; ++ni)
#pragma unroll
    for (int ks = 0; ks < 2; ++ks)
      bg[ni][ks] = ldsfrag(lB, wn * 64 + QN * 32 + ni * 16 + lr, ks * 4 + lk);
  stage();
  GFENCE; __builtin_amdgcn_s_barrier(); GFENCE;
  __builtin_amdgcn_s_setprio(1);
#pragma unroll
  for (int mi = 0; mi < 4; ++mi)
#pragma unroll
    for (int ni = 0; ni < 2; ++ni) {
      acc[QM * 4 + mi][QN * 2 + ni] = __builtin_amdgcn_mfma_f32_16x16x32_bf16(
          af[mi][0], bg[ni][0], acc[QM * 4 + mi][QN * 2 + ni], 0, 0, 0);
      acc[QM * 4 + mi][QN * 2 + ni] = __builtin_amdgcn_mfma_f32_16x16x32_bf16(
          af[mi][1], bg[ni][1], acc[QM * 4 + mi][QN * 2 + ni], 0, 0, 0);
    }
  __builtin_amdgcn_s_setprio(0);
  boundary();
  GFENCE; __builtin_amdgcn_s_barrier(); GFENCE;
}

template<bool HAS_BIAS, int MODE>
__global__ __launch_bounds__(512, 1) void gemm256(
    const u16* __restrict__ A, const u16* __restrict__ B,
    const float* __restrict__ bias, const float* __restrict__ bias2,
    void* __restrict__ Cv, void* __restrict__ Cv2,
    int M, int N, int K, long sA, long sB, long sC, float scale) {
  __shared__ __align__(16) u16 lds[2][2][256 * 64];
  // T1 swizzle: dispatch id -> XCD-contiguous chunk, z-major then x-major.
  const int nx = gridDim.x, ny = gridDim.y;
  const int did = blockIdx.x + nx * (blockIdx.y + ny * blockIdx.z);
  const int cpx = (nx * ny * gridDim.z) >> 3;       // all grids %8 == 0
  const int nf = (did & 7) * cpx + (did >> 3);
  const int b = nf / (nx * ny);
  const int rr = nf % (nx * ny);
  const int bm = (rr / ny) * 256;
  const int bn = (rr % ny) * 256;

  const u16* Ab = A + (long)b * sA;
  const u16* Bb = B + (long)b * sB;
  const int tid = threadIdx.x;
  const int lane = tid & 63, wave = tid >> 6;
  const int wm = wave >> 2, wn = wave & 3;
  const int lr = lane & 15, lk = lane >> 4;
  const int NT = K >> 6;

  f32x4 acc[8][4] = {};

  // prologue: tile0 all 4 chunks -> buf0, tile1 early chunks -> buf1
  stage_chunk<0, 0>(Ab, bm, K, 0, lds[0][0], tid);
  stage_chunk<1, 0>(Bb, bn, K, 0, lds[0][1], tid);
  stage_chunk<0, 1>(Ab, bm, K, 0, lds[0][0], tid);
  stage_chunk<1, 1>(Bb, bn, K, 0, lds[0][1], tid);
  if (NT > 1) {
    stage_chunk<0, 0>(Ab, bm, K, 64, lds[1][0], tid);
    stage_chunk<1, 0>(Bb, bn, K, 64, lds[1][1], tid);
    asm volatile("s_waitcnt vmcnt(4)" ::: "memory");
  } else {
    asm volatile("s_waitcnt vmcnt(0)" ::: "memory");
  }
  __builtin_amdgcn_s_barrier();
  GFENCE;

  for (int t = 0; t < NT; ++t) {
    const int cur = t & 1, nxt = cur ^ 1;
    const int k1 = (t + 1) << 6, k2 = (t + 2) << 6;
    const u16* lA = lds[cur][0];
    const u16* lB = lds[cur][1];
    phase_fn<0, 0>(lA, lB, acc, wm, wn, lr, lk,
        [&]() { if (t + 1 < NT) stage_chunk<0, 1>(Ab, bm, K, k1, lds[nxt][0], tid); },
        [&]() {});
    phase_fn<0, 1>(lA, lB, acc, wm, wn, lr, lk,
        [&]() { if (t + 1 < NT) stage_chunk<1, 1>(Bb, bn, K, k1, lds[nxt][1], tid); },
        [&]() {});
    phase_fn<1, 0>(lA, lB, acc, wm, wn, lr, lk,
        [&]() { if (t + 2 < NT) stage_chunk<0, 0>(Ab, bm, K, k2, lds[cur][0], tid); },
        [&]() {});
    phase_fn<1, 1>(lA, lB, acc, wm, wn, lr, lk,
        [&]() { if (t + 2 < NT) stage_chunk<1, 0>(Bb, bn, K, k2, lds[cur][1], tid); },
        [&]() {
          if (t + 2 < NT)      { asm volatile("s_waitcnt vmcnt(4)" ::: "memory"); }
          else if (t + 1 < NT) { asm volatile("s_waitcnt vmcnt(0)" ::: "memory"); }
        });
  }

  // epilogue: C/D layout col = lane&15, row = (lane>>4)*4 + j
  const bool vside = (MODE == 2) && (bn >= 1024);
  const int ldC = (MODE == 2) ? 1024 : N;
  const long cb = (long)b * sC;
  if (vside) {
    // transposed V store: Cv2[batch][col][row], 2048 rows/batch, ld 2048
#pragma unroll
    for (int mi = 0; mi < 8; ++mi) {
#pragma unroll
      for (int ni = 0; ni < 4; ++ni) {
        const int row0 = bm + wm * 128 + mi * 16 + (lk << 2);
        const int col2 = (bn - 1024) + wn * 64 + ni * 16 + lr;
        const float bvx = HAS_BIAS ? bias2[col2] : 0.f;
        u16x4 pk;
#pragma unroll
        for (int j = 0; j < 4; ++j) pk[j] = f2bf(acc[mi][ni][j] * scale + bvx);
        const long ad = (long)(row0 >> 11) * (2048L * 1024) +
                        (long)col2 * 2048 + (row0 & 2047);
        *(u16x4*)&((u16*)Cv2)[ad] = pk;
      }
    }
  } else {
#pragma unroll
    for (int mi = 0; mi < 8; ++mi) {
#pragma unroll
      for (int ni = 0; ni < 4; ++ni) {
        const int row0 = bm + wm * 128 + mi * 16 + (lk << 2);
        const int col = bn + wn * 64 + ni * 16 + lr;
        const float bvx = HAS_BIAS ? bias[col] : 0.f;
#pragma unroll
        for (int j = 0; j < 4; ++j) {
          const float x = acc[mi][ni][j] * scale + bvx;
          if (MODE == 1)
            ((float*)Cv)[cb + (long)(row0 + j) * ldC + col] = x;
          else
            ((u16*)Cv)[cb + (long)(row0 + j) * ldC + col] = f2bf(x);
        }
      }
    }
  }
}

// ---------------------------------------------------------------------------
extern "C" void kernel_launch(void* const* d_in, const int* in_sizes, int n_in,
                              void* d_out, int out_size, void* d_ws, size_t ws_size,
                              hipStream_t stream) {
  const float* query = (const float*)d_in[0];   // [8,2048,1024]
  const float* kv    = (const float*)d_in[1];   // [8,2048,1024]
  const int*   mask  = (const int*)d_in[2];     // [8,2048,2048]
  const float* Wq = (const float*)d_in[3];
  const float* bq = (const float*)d_in[4];
  const float* Wk = (const float*)d_in[5];
  const float* bk = (const float*)d_in[6];
  const float* Wv = (const float*)d_in[7];
  const float* bv = (const float*)d_in[8];
  const float* Wo = (const float*)d_in[9];
  const float* bo = (const float*)d_in[10];
  float* out = (float*)d_out;

  char* ws = (char*)d_ws;
  const size_t MB = (size_t)1 << 20;
  u16* qbf  = (u16*)(ws + 0);          // 32MB query bf16; later reused as O
  u16* kvbf = (u16*)(ws + 32 * MB);    // 32MB kv bf16
  u16* wq   = (u16*)(ws + 64 * MB);    // 2MB
  u16* wk   = (u16*)(ws + 66 * MB);    // 2MB  (wk,wv contiguous = wkv [2048][1024])
  u16* wv   = (u16*)(ws + 68 * MB);    // 2MB
  u16* wo   = (u16*)(ws + 70 * MB);    // 2MB
  u16* Q    = (u16*)(ws + 72 * MB);    // 32MB
  u16* Kb   = (u16*)(ws + 104 * MB);   // 32MB
  u16* Vt   = (u16*)(ws + 136 * MB);   // 32MB  [8][1024][2048] bf16
  u16* S    = (u16*)(ws + 168 * MB);   // 64MB  [8][2048][2048] bf16
  u16* O    = qbf;                     // [8][2048][1024] bf16 (qbf dead by then)

  const long sQK = (long)2048 * 1024;
  const long sS  = (long)2048 * 2048;

  // 1) converts
  cvt_f32_to_bf16<<<8192, 256, 0, stream>>>(query, qbf, 2097152);
  cvt_f32_to_bf16<<<8192, 256, 0, stream>>>(kv, kvbf, 2097152);
  cvt_f32_to_bf16<<<512, 256, 0, stream>>>(Wq, wq, 131072);
  cvt_f32_to_bf16<<<512, 256, 0, stream>>>(Wk, wk, 131072);
  cvt_f32_to_bf16<<<512, 256, 0, stream>>>(Wv, wv, 131072);
  cvt_f32_to_bf16<<<512, 256, 0, stream>>>(Wo, wo, 131072);

  // 2) Q projection: M=16384, N=1024, K=1024
  gemm256<true, 0><<<dim3(64, 4, 1), 512, 0, stream>>>(
      qbf, wq, bq, nullptr, Q, nullptr, 16384, 1024, 1024, 0, 0, 0, 1.f);

  // 3) merged K+V projection: N=2048 (B = wk||wv contiguous).
  //    cols<1024 -> Kb [16384][1024]; cols>=1024 -> Vt transposed.
  gemm256<true, 2><<<dim3(64, 8, 1), 512, 0, stream>>>(
      kvbf, wk, bk, bv, Kb, Vt, 16384, 2048, 1024, 0, 0, 0, 1.f);

  // 4) S = (Q K^T) * 1/32 (mask applied in softmax)
  gemm256<false, 0><<<dim3(8, 8, 8), 512, 0, stream>>>(
      Q, Kb, nullptr, nullptr, S, nullptr, 2048, 2048, 1024, sQK, sQK, sS, 0.03125f);

  // 5) masked row softmax (in place on S)
  softmax_mask_rows<<<16384, 256, 0, stream>>>(S, mask);

  // 6) O = P @ V   (B = Vt [1024 n-rows][2048 k], batch stride sQK)
  gemm256<false, 0><<<dim3(8, 4, 8), 512, 0, stream>>>(
      S, Vt, nullptr, nullptr, O, nullptr, 2048, 1024, 2048, sS, sQK, sQK, 1.f);

  // 7) out = O @ Wo^T + bo   (fp32 output)
  gemm256<true, 1><<<dim3(64, 4, 1), 512, 0, stream>>>(
      O, wo, bo, nullptr, out, nullptr, 16384, 1024, 1024, 0, 0, 0, 1.f);
}